// Round 12
// baseline (889.828 us; speedup 1.0000x reference)
//
#include <hip/hip_runtime.h>
#include <hip/hip_bf16.h>

#define BATCH   16
#define N_ANC   8649      // 31*31*9
#define SORT_N  16384     // padded pow2
#define PRE     6000
#define POST    1500
#define ROWW    188       // u32 words per mask row (752 B, 47 uint4)
#define MROWS   6016      // rows incl. 16 pad rows (group 187)
#define NGRP    188       // 188 groups of 32 rows
#define GQUADS  1504      // uint4 per 32-row group (32*47)

// ---------------- Kernel 1: fused decode + per-chunk bitonic sort ----------------
// Block (b,c) decodes chunk c's keys directly into LDS (and writes boxes),
// sorts 8192 keys (c0 asc, c1 desc via global-index direction), writes chunk.
__global__ __launch_bounds__(1024) void k_sortdecode(
    const float* __restrict__ deltas, const float* __restrict__ probs,
    const float* __restrict__ anchors, float4* __restrict__ boxes,
    unsigned long long* __restrict__ keys)
{
    __shared__ unsigned long long sb[8192];   // 64 KB
    int b = blockIdx.x >> 1;
    int c = blockIdx.x & 1;
    int base = c * 8192;

    for (int i = threadIdx.x; i < 8192; i += 1024) {
        int n = base + i;
        unsigned long long key = ~0ULL;
        if (n < N_ANC) {
            float s = probs[(size_t)b * N_ANC + n];
            unsigned int bits = __float_as_uint(s);
            unsigned int u = bits ^ ((bits & 0x80000000u) ? 0xFFFFFFFFu : 0x80000000u);
            key = ((unsigned long long)(~u) << 32) | (unsigned int)n;

            float4 a = ((const float4*)anchors)[n];
            float4 d = ((const float4*)deltas)[(size_t)b * N_ANC + n];
            float dy = d.x * 0.1f, dx = d.y * 0.1f, dh = d.z * 0.2f, dw = d.w * 0.2f;
            float ah = a.z - a.x, aw = a.w - a.y;
            float cy = a.x + 0.5f * ah, cx = a.y + 0.5f * aw;
            float bh = expf(dh) * ah, bw = expf(dw) * aw;
            float bcy = dy * ah + cy, bcx = dx * aw + cx;
            float y1 = bcy - 0.5f * bh, x1 = bcx - 0.5f * bw;
            boxes[(size_t)b * N_ANC + n] = make_float4(y1, x1, y1 + bh, x1 + bw);
        }
        sb[i] = key;
    }
    __syncthreads();

    for (int k = 2; k <= 8192; k <<= 1) {
        for (int j = k >> 1; j >= 1; j >>= 1) {
            for (int p = threadIdx.x; p < 4096; p += 1024) {
                int i  = ((p & ~(j - 1)) << 1) | (p & (j - 1));
                int gi = (c << 13) | i;
                bool asc = ((gi & k) == 0);
                unsigned long long a = sb[i], b2 = sb[i | j];
                bool sw = asc ? (a > b2) : (a < b2);
                if (sw) { sb[i] = b2; sb[i | j] = a; }
            }
            __syncthreads();
        }
    }
    unsigned long long* g = keys + (size_t)b * SORT_N + base;
    for (int t = threadIdx.x; t < 8192; t += 1024) g[t] = sb[t];
}

// ---------------- Kernel 2: merge (1 block / batch), keep top 6016 ----------------
__global__ __launch_bounds__(1024) void k_sort_merge(unsigned long long* __restrict__ keys)
{
    __shared__ unsigned long long sb[8192];   // 64 KB
    int b = blockIdx.x;
    unsigned long long* kb = keys + (size_t)b * SORT_N;

    for (int p = threadIdx.x; p < 8192; p += 1024) {
        unsigned long long a = kb[p], b2 = kb[p + 8192];
        if (a > b2) { kb[p] = b2; kb[p + 8192] = a; }
    }
    __syncthreads();

    for (int t = threadIdx.x; t < 8192; t += 1024) sb[t] = kb[t];
    __syncthreads();
    for (int j = 4096; j >= 1; j >>= 1) {
        for (int p = threadIdx.x; p < 4096; p += 1024) {
            int i = ((p & ~(j - 1)) << 1) | (p & (j - 1));
            unsigned long long a = sb[i], b2 = sb[i | j];
            if (a > b2) { sb[i] = b2; sb[i | j] = a; }
        }
        __syncthreads();
    }
    for (int t = threadIdx.x; t < 6016; t += 1024) kb[t] = sb[t];
}

// ---------------- Kernel 3: gather sorted boxes/scores ----------------
__global__ __launch_bounds__(256) void k_gather(
    const unsigned long long* __restrict__ keys, const float4* __restrict__ boxes,
    const float* __restrict__ probs,
    float4* __restrict__ sboxes, float* __restrict__ sscores)
{
    int t = blockIdx.x * 256 + threadIdx.x;
    if (t >= BATCH * PRE) return;
    int b = t / PRE;
    int r = t - b * PRE;
    unsigned long long k = keys[(size_t)b * SORT_N + r];
    int idx = (int)(k & 0xFFFFFFFFu);
    sboxes[(size_t)b * PRE + r]  = boxes[(size_t)b * N_ANC + idx];
    sscores[(size_t)b * PRE + r] = probs[(size_t)b * N_ANC + idx];
}

// ---------------- Kernel 4: IoU bit-matrix, 512x256 tiles, 2 rows/thread ----------
// Guarded-rcp division: exact vs reference by construction (band fallback).
template<bool PRED>
__device__ __forceinline__ unsigned int iou_word(
    const float4* __restrict__ jb, const float* __restrict__ ja,
    int wq, float4 bi, float ai, int trow)
{
    unsigned int bits = 0u;
    #pragma unroll
    for (int jj = 0; jj < 32; jj++) {
        int lj = wq * 32 + jj;
        float4 bx = jb[lj];
        float ih = fmaxf(fminf(bi.z, bx.z) - fmaxf(bi.x, bx.x), 0.0f);
        float iw = fmaxf(fminf(bi.w, bx.w) - fmaxf(bi.y, bx.y), 0.0f);
        float inter = ih * iw;
        float denom = ai + ja[lj] - inter + 1e-8f;
        float ap = inter * __builtin_amdgcn_rcpf(denom);
        float d = ap - 0.7f;
        bool set;
        if (fabsf(d) < 1e-6f) set = (inter / denom > 0.7f);  // rare exact path
        else                  set = (d > 0.0f);
        if (PRED) set = set && (lj > trow);
        if (set) bits |= (1u << jj);
    }
    return bits;
}

__global__ __launch_bounds__(256) void k_iou(
    const float4* __restrict__ sboxes, unsigned int* __restrict__ mask)
{
    int it = blockIdx.x;            // 512-row tile, 0..11
    int jt = blockIdx.y;            // 256-col tile, 0..23
    int b  = blockIdx.z;
    int ibase  = it << 9;
    int jbase0 = jt << 8;
    if (jbase0 < ibase) return;     // no j > i in tile

    __shared__ float4 jb[256];
    __shared__ float  ja[256];
    int t = threadIdx.x;
    int j = jbase0 + t;
    float4 bj = (j < PRE) ? sboxes[(size_t)b * PRE + j]
                          : make_float4(-2e6f, -2e6f, -1.5e6f, -1.5e6f); // far dummy
    jb[t] = bj;
    ja[t] = (bj.z - bj.x) * (bj.w - bj.y);
    __syncthreads();

    int i0 = ibase + t;
    int i1 = ibase + 256 + t;
    bool do1 = (jbase0 >= ibase + 256);   // row1 has j>i only then

    float4 b0 = (i0 < PRE) ? sboxes[(size_t)b * PRE + i0] : make_float4(0, 0, 0, 0);
    float  a0 = (b0.z - b0.x) * (b0.w - b0.y);
    float4 b1 = (do1 && i1 < PRE) ? sboxes[(size_t)b * PRE + i1] : make_float4(0, 0, 0, 0);
    float  a1 = (b1.z - b1.x) * (b1.w - b1.y);

    unsigned int w0[8], w1[8];
    if (jbase0 == ibase) {
        // row0 same-tile predicated; row1 dead here
        #pragma unroll
        for (int wq = 0; wq < 8; wq++) w0[wq] = iou_word<true>(jb, ja, wq, b0, a0, t);
    } else if (jbase0 == ibase + 256) {
        // row0 fully interior; row1 same-tile predicated
        #pragma unroll
        for (int wq = 0; wq < 8; wq++) {
            w0[wq] = iou_word<false>(jb, ja, wq, b0, a0, 0);
            w1[wq] = iou_word<true>(jb, ja, wq, b1, a1, t);
        }
    } else {
        #pragma unroll
        for (int wq = 0; wq < 8; wq++) {
            w0[wq] = iou_word<false>(jb, ja, wq, b0, a0, 0);
            w1[wq] = iou_word<false>(jb, ja, wq, b1, a1, 0);
        }
    }

    if (i0 < PRE) {
        unsigned int* row = mask + ((size_t)b * MROWS + i0) * ROWW + jt * 8;
        ((uint4*)row)[0] = make_uint4(w0[0], w0[1], w0[2], w0[3]);
        if (jt < 23) ((uint4*)row)[1] = make_uint4(w0[4], w0[5], w0[6], w0[7]);
    }
    if (do1 && i1 < PRE) {
        unsigned int* row = mask + ((size_t)b * MROWS + i1) * ROWW + jt * 8;
        ((uint4*)row)[0] = make_uint4(w1[0], w1[1], w1[2], w1[3]);
        if (jt < 23) ((uint4*)row)[1] = make_uint4(w1[4], w1[5], w1[6], w1[7]);
    }
}

// ---------------- Kernel 5: 4-wave producer/consumer scan + fused output ----------
// Thread t owns state word t. Group rows double-buffered in LDS via reg staging.
// Kept indices recorded in LDS; this block writes batch b's final output.
__global__ __launch_bounds__(256, 1) void k_scan(
    const unsigned int* __restrict__ mask, const float4* __restrict__ sboxes,
    const float* __restrict__ sscores, float* __restrict__ out)
{
    __shared__ unsigned int rows[2][32 * ROWW];   // 2 x 24064 B
    __shared__ unsigned int sw_lds[2];
    __shared__ int kept_lds[POST];
    int b   = blockIdx.x;
    int tid = threadIdx.x;
    const uint4* mb = (const uint4*)(mask + (size_t)b * MROWS * ROWW);

    if (tid < 2) sw_lds[tid] = 0u;

    uint4 sreg[6];
    #pragma unroll
    for (int i = 0; i < 6; i++) {
        int q = tid + i * 256;
        sreg[i] = (q < GQUADS) ? mb[q] : make_uint4(0, 0, 0, 0);
    }
    #pragma unroll
    for (int i = 0; i < 6; i++) {
        int q = tid + i * 256;
        if (q < GQUADS) ((uint4*)rows[0])[q] = sreg[i];
    }
    __syncthreads();

    unsigned int st_word = 0u;
    int cnt = 0;

    for (int g = 0; g < NGRP; g++) {
        int cur = g & 1;
        bool have_next = (g + 1 < NGRP);

        if (have_next) {
            const uint4* src = mb + (size_t)(g + 1) * GQUADS;
            #pragma unroll
            for (int i = 0; i < 6; i++) {
                int q = tid + i * 256;
                sreg[i] = (q < GQUADS) ? src[q] : make_uint4(0, 0, 0, 0);
            }
        }

        unsigned int tri[32];
        #pragma unroll
        for (int k = 0; k < 32; k++) tri[k] = rows[cur][k * ROWW + g];

        unsigned int sw = sw_lds[cur];

        // resolve: uncapped fast chain, rare capped redo (exact cap semantics)
        int need_n = POST - cnt;
        unsigned int valid = (g == NGRP - 1) ? 0xFFFFu : 0xFFFFFFFFu;
        unsigned int alive = ~sw & valid;
        unsigned int km = 0u;
        #pragma unroll
        for (int k = 0; k < 32; k++) {
            unsigned int bit = (alive >> k) & 1u;
            km |= bit << k;
            alive &= ~((0u - bit) & tri[k]);
        }
        int kc = __popc(km);
        if (kc > need_n) {                 // uniform, rare
            alive = ~sw & valid; km = 0u; kc = 0;
            #pragma unroll
            for (int k = 0; k < 32; k++) {
                unsigned int bit = (alive >> k) & 1u;
                bit &= (kc < need_n) ? 1u : 0u;
                kc += (int)bit;
                km |= bit << k;
                alive &= ~((0u - bit) & tri[k]);
            }
        }

        if (tid < 32 && ((km >> tid) & 1u))
            kept_lds[cnt + __popc(km & ((1u << tid) - 1u))] = g * 32 + tid;
        cnt += kc;

        if (tid < ROWW) {
            unsigned int acc = 0u;
            #pragma unroll
            for (int k = 0; k < 32; k++)
                acc |= rows[cur][k * ROWW + tid] & (0u - ((km >> k) & 1u));
            st_word |= acc;
        }

        if (have_next && tid == g + 1) sw_lds[(g + 1) & 1] = st_word;

        if (have_next) {
            uint4* dst = (uint4*)rows[cur ^ 1];
            #pragma unroll
            for (int i = 0; i < 6; i++) {
                int q = tid + i * 256;
                if (q < GQUADS) dst[q] = sreg[i];
            }
        }
        __syncthreads();
    }

    // fused output: compact + clip (all POST slots written; poison-safe)
    for (int r = tid; r < POST; r += 256) {
        float4 v = make_float4(0, 0, 0, 0);
        float sc = 0.f;
        if (r < cnt) {
            int i = kept_lds[r];
            float4 bx = sboxes[(size_t)b * PRE + i];
            v.x = fminf(fmaxf(bx.x, 0.f), 1.f);
            v.y = fminf(fmaxf(bx.y, 0.f), 1.f);
            v.z = fminf(fmaxf(bx.z, 0.f), 1.f);
            v.w = fminf(fmaxf(bx.w, 0.f), 1.f);
            sc = sscores[(size_t)b * PRE + i];
        }
        ((float4*)out)[(size_t)b * POST + r] = v;
        out[(size_t)BATCH * POST * 4 + (size_t)b * POST + r] = sc;
    }
}

// ---------------- host ----------------
extern "C" void kernel_launch(void* const* d_in, const int* in_sizes, int n_in,
                              void* d_out, int out_size, void* d_ws, size_t ws_size,
                              hipStream_t stream)
{
    const float* deltas  = (const float*)d_in[0];
    const float* probs   = (const float*)d_in[1];
    const float* anchors = (const float*)d_in[2];
    float* out = (float*)d_out;

    char* ws = (char*)d_ws;
    size_t off = 0;
    auto alloc = [&](size_t bytes) {
        size_t o = off;
        off = (off + bytes + 255) & ~(size_t)255;
        return o;
    };
    float4* boxes            = (float4*)(ws + alloc((size_t)BATCH * N_ANC * 16));
    unsigned long long* keys = (unsigned long long*)(ws + alloc((size_t)BATCH * SORT_N * 8));
    float4* sboxes           = (float4*)(ws + alloc((size_t)BATCH * PRE * 16));
    float* sscores           = (float*)(ws + alloc((size_t)BATCH * PRE * 4));
    unsigned int* mask       = (unsigned int*)(ws + alloc((size_t)BATCH * MROWS * ROWW * 4));

    k_sortdecode<<<BATCH * 2, 1024, 0, stream>>>(deltas, probs, anchors, boxes, keys);
    k_sort_merge<<<BATCH, 1024, 0, stream>>>(keys);
    k_gather<<<(BATCH * PRE + 255) / 256, 256, 0, stream>>>(keys, boxes, probs, sboxes, sscores);
    k_iou<<<dim3(12, 24, BATCH), 256, 0, stream>>>(sboxes, mask);
    k_scan<<<BATCH, 256, 0, stream>>>(mask, sboxes, sscores, out);
}

// Round 13
// 640.909 us; speedup vs baseline: 1.3884x; 1.3884x over previous
//
#include <hip/hip_runtime.h>
#include <hip/hip_bf16.h>

#define BATCH   16
#define N_ANC   8649      // 31*31*9
#define SORT_N  16384     // padded pow2
#define PRE     6000
#define POST    1500
#define ROWW    188       // u32 words per mask row (752 B, 47 uint4)
#define MROWS   6016      // rows incl. 16 pad rows (group 187)
#define NGRP    188       // 188 groups of 32 rows
#define GQUADS  1504      // uint4 per 32-row group (32*47)
#define TI      256
#define TJ      256

// ---------------- Kernel 1: decode boxes + build sort keys ----------------
__global__ __launch_bounds__(256) void k_decode(
    const float* __restrict__ deltas, const float* __restrict__ probs,
    const float* __restrict__ anchors, float4* __restrict__ boxes,
    unsigned long long* __restrict__ keys)
{
    int t = blockIdx.x * 256 + threadIdx.x;
    if (t >= BATCH * SORT_N) return;
    int b = t / SORT_N;
    int n = t - b * SORT_N;
    if (n >= N_ANC) { keys[t] = ~0ULL; return; }

    float s = probs[(size_t)b * N_ANC + n];
    unsigned int bits = __float_as_uint(s);
    unsigned int u = bits ^ ((bits & 0x80000000u) ? 0xFFFFFFFFu : 0x80000000u);
    keys[(size_t)b * SORT_N + n] = ((unsigned long long)(~u) << 32) | (unsigned int)n;

    float4 a = ((const float4*)anchors)[n];
    float4 d = ((const float4*)deltas)[(size_t)b * N_ANC + n];
    float dy = d.x * 0.1f, dx = d.y * 0.1f, dh = d.z * 0.2f, dw = d.w * 0.2f;
    float ah = a.z - a.x, aw = a.w - a.y;
    float cy = a.x + 0.5f * ah, cx = a.y + 0.5f * aw;
    float bh = expf(dh) * ah, bw = expf(dw) * aw;
    float bcy = dy * ah + cy, bcx = dx * aw + cx;
    float y1 = bcy - 0.5f * bh, x1 = bcx - 0.5f * bw;
    boxes[(size_t)b * N_ANC + n] = make_float4(y1, x1, y1 + bh, x1 + bw);
}

// ---------------- Kernel 2a: per-chunk bitonic sort (2 blocks / batch) ----------------
__global__ __launch_bounds__(1024) void k_sort_chunk(unsigned long long* __restrict__ keys)
{
    __shared__ unsigned long long sb[8192];   // 64 KB
    int b = blockIdx.x >> 1;
    int c = blockIdx.x & 1;
    unsigned long long* g = keys + (size_t)b * SORT_N + c * 8192;

    for (int t = threadIdx.x; t < 8192; t += 1024) sb[t] = g[t];
    __syncthreads();
    for (int k = 2; k <= 8192; k <<= 1) {
        for (int j = k >> 1; j >= 1; j >>= 1) {
            for (int p = threadIdx.x; p < 4096; p += 1024) {
                int i  = ((p & ~(j - 1)) << 1) | (p & (j - 1));
                int gi = (c << 13) | i;
                bool asc = ((gi & k) == 0);
                unsigned long long a = sb[i], b2 = sb[i | j];
                bool sw = asc ? (a > b2) : (a < b2);
                if (sw) { sb[i] = b2; sb[i | j] = a; }
            }
            __syncthreads();
        }
    }
    for (int t = threadIdx.x; t < 8192; t += 1024) g[t] = sb[t];
}

// ---------------- Kernel 2b: merge (1 block / batch), keep top 6016 ----------------
__global__ __launch_bounds__(1024) void k_sort_merge(unsigned long long* __restrict__ keys)
{
    __shared__ unsigned long long sb[8192];   // 64 KB
    int b = blockIdx.x;
    unsigned long long* kb = keys + (size_t)b * SORT_N;

    for (int p = threadIdx.x; p < 8192; p += 1024) {
        unsigned long long a = kb[p], b2 = kb[p + 8192];
        if (a > b2) { kb[p] = b2; kb[p + 8192] = a; }
    }
    __syncthreads();

    for (int t = threadIdx.x; t < 8192; t += 1024) sb[t] = kb[t];
    __syncthreads();
    for (int j = 4096; j >= 1; j >>= 1) {
        for (int p = threadIdx.x; p < 4096; p += 1024) {
            int i = ((p & ~(j - 1)) << 1) | (p & (j - 1));
            unsigned long long a = sb[i], b2 = sb[i | j];
            if (a > b2) { sb[i] = b2; sb[i | j] = a; }
        }
        __syncthreads();
    }
    for (int t = threadIdx.x; t < 6016; t += 1024) kb[t] = sb[t];
}

// ---------------- Kernel 3: gather sorted boxes/scores ----------------
__global__ __launch_bounds__(256) void k_gather(
    const unsigned long long* __restrict__ keys, const float4* __restrict__ boxes,
    const float* __restrict__ probs,
    float4* __restrict__ sboxes, float* __restrict__ sscores)
{
    int t = blockIdx.x * 256 + threadIdx.x;
    if (t >= BATCH * PRE) return;
    int b = t / PRE;
    int r = t - b * PRE;
    unsigned long long k = keys[(size_t)b * SORT_N + r];
    int idx = (int)(k & 0xFFFFFFFFu);
    sboxes[(size_t)b * PRE + r]  = boxes[(size_t)b * N_ANC + idx];
    sscores[(size_t)b * PRE + r] = probs[(size_t)b * N_ANC + idx];
}

// ---------------- Kernel 4: IoU bit-matrix, 256x256 tiles (round-10 shape) ----------
// Division-free decision: t = fma(-0.7, denom, inter) has the EXACT sign of
// (iou_real - 0.7). The reference's fl(inter/denom) > 0.7f can only disagree
// within |iou-0.7| <~ 6e-8; band |t| < denom*3e-7 (5x wider) falls back to the
// exact expression in an execz-skipped branch (~never taken).
template<bool PRED>
__device__ __forceinline__ unsigned int iou_word(
    const float4* __restrict__ jb, const float* __restrict__ ja,
    int wq, float4 bi, float ai, int trow)
{
    unsigned int bits = 0u, band = 0u;
    #pragma unroll
    for (int jj = 0; jj < 32; jj++) {
        int lj = wq * 32 + jj;
        float4 bx = jb[lj];
        float ih = fmaxf(fminf(bi.z, bx.z) - fmaxf(bi.x, bx.x), 0.0f);
        float iw = fmaxf(fminf(bi.w, bx.w) - fmaxf(bi.y, bx.y), 0.0f);
        float inter = ih * iw;
        float denom = ai + ja[lj] - inter + 1e-8f;
        float tt = __builtin_fmaf(-0.7f, denom, inter);
        bool pred = (!PRED) || (lj > trow);
        if ((tt > 0.0f) && pred) bits |= (1u << jj);
        if ((fabsf(tt) < denom * 3e-7f) && pred) band |= (1u << jj);
    }
    if (band) {                              // cold: exact-path fixup
        #pragma unroll 1
        for (int jj = 0; jj < 32; jj++) {
            if ((band >> jj) & 1u) {
                int lj = wq * 32 + jj;
                float4 bx = jb[lj];
                float ih = fmaxf(fminf(bi.z, bx.z) - fmaxf(bi.x, bx.x), 0.0f);
                float iw = fmaxf(fminf(bi.w, bx.w) - fmaxf(bi.y, bx.y), 0.0f);
                float inter = ih * iw;
                float denom = ai + ja[lj] - inter + 1e-8f;
                if (inter / denom > 0.7f) bits |= (1u << jj);
                else                      bits &= ~(1u << jj);
            }
        }
    }
    return bits;
}

__global__ __launch_bounds__(256) void k_iou(
    const float4* __restrict__ sboxes, unsigned int* __restrict__ mask)
{
    int it = blockIdx.x;   // row tile 0..23
    int jt = blockIdx.y;   // col tile 0..23
    int b  = blockIdx.z;
    if (jt < it) return;   // lower-triangle tiles never consumed by scan

    __shared__ float4 jb[TJ];
    __shared__ float  ja[TJ];
    int t = threadIdx.x;
    int j = jt * TJ + t;
    float4 bj = (j < PRE) ? sboxes[(size_t)b * PRE + j]
                          : make_float4(-2e6f, -2e6f, -1.5e6f, -1.5e6f); // far dummy, area>0
    jb[t] = bj;
    ja[t] = (bj.z - bj.x) * (bj.w - bj.y);
    __syncthreads();

    int i = it * TI + t;
    if (i >= PRE) return;
    float4 bi = sboxes[(size_t)b * PRE + i];
    float areai = (bi.z - bi.x) * (bi.w - bi.y);

    unsigned int w[8];
    if (jt > it) {
        for (int wq = 0; wq < 8; wq++)
            w[wq] = iou_word<false>(jb, ja, wq, bi, areai, 0);
    } else {
        for (int wq = 0; wq < 8; wq++) {
            int jbase = jt * TJ + wq * 32;
            w[wq] = (jbase + 31 > i) ? iou_word<true>(jb, ja, wq, bi, areai, t) : 0u;
        }
    }

    unsigned int* row = mask + ((size_t)b * MROWS + i) * ROWW + jt * 8;
    ((uint4*)row)[0] = make_uint4(w[0], w[1], w[2], w[3]);
    if (jt < 23) ((uint4*)row)[1] = make_uint4(w[4], w[5], w[6], w[7]);
}

// ---------------- Kernel 5: 4-wave producer/consumer group scan (round-10 form) ----
__global__ __launch_bounds__(256, 1) void k_scan(
    const unsigned int* __restrict__ mask,
    int* __restrict__ out_idx, int* __restrict__ out_cnt)
{
    __shared__ unsigned int rows[2][32 * ROWW];   // 2 x 24064 B
    __shared__ unsigned int sw_lds[2];
    int b   = blockIdx.x;
    int tid = threadIdx.x;
    const uint4* mb = (const uint4*)(mask + (size_t)b * MROWS * ROWW);

    if (tid < 2) sw_lds[tid] = 0u;

    uint4 sreg[6];
    #pragma unroll
    for (int i = 0; i < 6; i++) {
        int q = tid + i * 256;
        sreg[i] = (q < GQUADS) ? mb[q] : make_uint4(0, 0, 0, 0);
    }
    #pragma unroll
    for (int i = 0; i < 6; i++) {
        int q = tid + i * 256;
        if (q < GQUADS) ((uint4*)rows[0])[q] = sreg[i];
    }
    __syncthreads();

    unsigned int st_word = 0u;    // this thread's owned state word (tid < ROWW)
    int cnt = 0;
    int* oi = out_idx + b * POST;

    for (int g = 0; g < NGRP; g++) {
        int cur = g & 1;
        bool have_next = (g + 1 < NGRP);

        if (have_next) {
            const uint4* src = mb + (size_t)(g + 1) * GQUADS;
            #pragma unroll
            for (int i = 0; i < 6; i++) {
                int q = tid + i * 256;
                sreg[i] = (q < GQUADS) ? src[q] : make_uint4(0, 0, 0, 0);
            }
        }

        unsigned int tri[32];
        #pragma unroll
        for (int k = 0; k < 32; k++) tri[k] = rows[cur][k * ROWW + g];

        unsigned int sw = sw_lds[cur];

        int need_n = POST - cnt;
        unsigned int valid = (g == NGRP - 1) ? 0xFFFFu : 0xFFFFFFFFu;
        unsigned int alive = ~sw & valid;
        unsigned int km2 = 0u;
        int cum = 0;
        #pragma unroll
        for (int k = 0; k < 32; k++) {
            unsigned int bit = (alive >> k) & 1u;
            bit &= (cum < need_n) ? 1u : 0u;    // cap: dropped rows don't suppress
            cum += (int)bit;
            km2 |= bit << k;
            alive &= ~((0u - bit) & tri[k]);
        }

        if (tid < 32 && ((km2 >> tid) & 1u))
            oi[cnt + __popc(km2 & ((1u << tid) - 1u))] = g * 32 + tid;
        cnt += cum;

        if (tid < ROWW) {
            unsigned int acc = 0u;
            #pragma unroll
            for (int k = 0; k < 32; k++)
                acc |= rows[cur][k * ROWW + tid] & (0u - ((km2 >> k) & 1u));
            st_word |= acc;
        }

        if (have_next && tid == g + 1) sw_lds[(g + 1) & 1] = st_word;

        if (have_next) {
            uint4* dst = (uint4*)rows[cur ^ 1];
            #pragma unroll
            for (int i = 0; i < 6; i++) {
                int q = tid + i * 256;
                if (q < GQUADS) dst[q] = sreg[i];
            }
        }
        __syncthreads();
    }
    if (tid == 0) out_cnt[b] = cnt;
}

// ---------------- Kernel 6: compact + clip output ----------------
__global__ __launch_bounds__(256) void k_out(
    const float4* __restrict__ sboxes, const float* __restrict__ sscores,
    const int* __restrict__ out_idx, const int* __restrict__ out_cnt,
    float* __restrict__ out)
{
    int t = blockIdx.x * 256 + threadIdx.x;
    if (t >= BATCH * POST) return;
    int b = t / POST;
    int r = t - b * POST;
    float4 v = make_float4(0, 0, 0, 0);
    float sc = 0.f;
    if (r < out_cnt[b]) {
        int i = out_idx[b * POST + r];
        float4 bx = sboxes[(size_t)b * PRE + i];
        v.x = fminf(fmaxf(bx.x, 0.f), 1.f);
        v.y = fminf(fmaxf(bx.y, 0.f), 1.f);
        v.z = fminf(fmaxf(bx.z, 0.f), 1.f);
        v.w = fminf(fmaxf(bx.w, 0.f), 1.f);
        sc = sscores[(size_t)b * PRE + i];
    }
    ((float4*)out)[t] = v;                  // roi_bboxes
    out[(size_t)BATCH * POST * 4 + t] = sc; // roi_scores
}

// ---------------- host ----------------
extern "C" void kernel_launch(void* const* d_in, const int* in_sizes, int n_in,
                              void* d_out, int out_size, void* d_ws, size_t ws_size,
                              hipStream_t stream)
{
    const float* deltas  = (const float*)d_in[0];
    const float* probs   = (const float*)d_in[1];
    const float* anchors = (const float*)d_in[2];
    float* out = (float*)d_out;

    char* ws = (char*)d_ws;
    size_t off = 0;
    auto alloc = [&](size_t bytes) {
        size_t o = off;
        off = (off + bytes + 255) & ~(size_t)255;
        return o;
    };
    float4* boxes            = (float4*)(ws + alloc((size_t)BATCH * N_ANC * 16));
    unsigned long long* keys = (unsigned long long*)(ws + alloc((size_t)BATCH * SORT_N * 8));
    float4* sboxes           = (float4*)(ws + alloc((size_t)BATCH * PRE * 16));
    float* sscores           = (float*)(ws + alloc((size_t)BATCH * PRE * 4));
    unsigned int* mask       = (unsigned int*)(ws + alloc((size_t)BATCH * MROWS * ROWW * 4));
    int* oidx                = (int*)(ws + alloc((size_t)BATCH * POST * 4));
    int* ocnt                = (int*)(ws + alloc((size_t)BATCH * 4));

    k_decode<<<(BATCH * SORT_N + 255) / 256, 256, 0, stream>>>(deltas, probs, anchors, boxes, keys);
    k_sort_chunk<<<BATCH * 2, 1024, 0, stream>>>(keys);
    k_sort_merge<<<BATCH, 1024, 0, stream>>>(keys);
    k_gather<<<(BATCH * PRE + 255) / 256, 256, 0, stream>>>(keys, boxes, probs, sboxes, sscores);
    k_iou<<<dim3(24, 24, BATCH), 256, 0, stream>>>(sboxes, mask);
    k_scan<<<BATCH, 256, 0, stream>>>(mask, oidx, ocnt);
    k_out<<<(BATCH * POST + 255) / 256, 256, 0, stream>>>(sboxes, sscores, oidx, ocnt, out);
}